// Round 5
// baseline (622.203 us; speedup 1.0000x reference)
//
#include <hip/hip_runtime.h>

#define IH 126
#define IW 126
#define HW 15876      // 126*126
#define OH 124
#define OW 124
#define OHW 15376     // 124*124

// ---------------------------------------------------------------- conv_in
__global__ __launch_bounds__(256) void conv_in_kernel(
    const float* __restrict__ x, const float* __restrict__ w,
    const float* __restrict__ b, float* __restrict__ y)
{
  int pix = blockIdx.x * 256 + threadIdx.x;
  if (pix >= HW) return;
  int oc = blockIdx.y;                 // wave-uniform -> weights become s_loads
  int h  = pix / IW;
  int wc = pix - h * IW;
  const float* wp = w + oc * 27;
  float acc = b[oc];
#pragma unroll
  for (int ci = 0; ci < 3; ci++)
#pragma unroll
    for (int ky = 0; ky < 3; ky++)
#pragma unroll
      for (int kx = 0; kx < 3; kx++)
        acc = fmaf(x[ci * 128 * 128 + (h + ky) * 128 + (wc + kx)],
                   wp[ci * 9 + ky * 3 + kx], acc);
  y[oc * HW + pix] = acc;
}

// ---------------------------------------------------------------- involution v5
// v4 + (a) xs -> [c][141] (odd pos-pitch): phase-A writes stride-1 (were 8-way
// conflicted at stride-68), B/D reads stay conflict-free; (b) wvs g-skew so
// phase-D's 4 g-addresses land in 4 distinct bank-quads (were 1 quad, 4-way).
__global__ __launch_bounds__(512, 4) void inv_kernel(
    const float* __restrict__ x, float* __restrict__ y,
    const float* __restrict__ wr, const float* __restrict__ br,
    const float* __restrict__ gam, const float* __restrict__ bet,
    const float* __restrict__ mu, const float* __restrict__ var,
    const float* __restrict__ wspan, const float* __restrict__ bspan)
{
  __shared__ __align__(16) float xs[64 * 141];   // 36,096 B  [c][pos 14x10+pad]
  __shared__ __align__(16) float wvs[6296];      // 25,184 B  skewed pair*32+g*8
  __shared__ float bsp_l[196];                   //    784 B
  float* tss = &wvs[5656];                       // [32][20] overlap tail (pairs>=176 written after barrier)
  float* ob  = &xs[0];                           // [64][33] alias in phase E

  int tid = threadIdx.x;
  int bx = blockIdx.x & 15, by = blockIdx.x >> 4;
  int ox0 = bx * 8, oy0 = by * 4;
  int xh0 = ox0 - 3, yh0 = oy0 - 3;

  // ---- Phase A: stage x halo (14 cols x 10 rows x 64 ch) + bspan
  if (tid < 196) bsp_l[tid] = bspan[tid];
  for (int idx = tid; idx < 140 * 64; idx += 512) {
    int c = idx / 140;
    int pos = idx - c * 140;
    int row = pos / 14;
    int col = pos - row * 14;
    int gy = yh0 + row, gx = xh0 + col;
    float v = 0.f;
    if (gy >= 0 && gy < IH && gx >= 0 && gx < IW)
      v = x[c * HW + gy * IW + gx];
    xs[c * 141 + pos] = v;             // lanes consecutive pos: stride-1, free
  }
  __syncthreads();

  int w_ = __builtin_amdgcn_readfirstlane(tid >> 6);  // wave 0..7
  int ln = tid & 63;
  int p  = ln & 31;                   // pixel 0..31 (upper 32 lanes duplicate)
  int prow = p >> 3, pcol = p & 7;
  int pc = (prow + 3) * 14 + (pcol + 3);

  // ---- Phase B: t = ReLU(BN(Wr.x)); wave w_ does cr = 2w_, 2w_+1 (uniform)
  {
    int cr0 = 2 * w_;
    const float* wa = wr + cr0 * 64;  // uniform -> s_load
    const float* wb = wa + 64;
    float a0 = 0.f, a1 = 0.f;
#pragma unroll
    for (int ci = 0; ci < 64; ci++) {
      float xv = xs[ci * 141 + pc];   // lanes: 32 distinct pc, 2-way dup: free
      a0 = fmaf(xv, wa[ci], a0);
      a1 = fmaf(xv, wb[ci], a1);
    }
    float s0 = gam[cr0]     * rsqrtf(var[cr0]     + 1e-5f);
    float s1 = gam[cr0 + 1] * rsqrtf(var[cr0 + 1] + 1e-5f);
    float t0 = (a0 + br[cr0]     - mu[cr0])     * s0 + bet[cr0];
    float t1 = (a1 + br[cr0 + 1] - mu[cr0 + 1]) * s1 + bet[cr0 + 1];
    if (ln < 32) {
      tss[p * 20 + cr0]     = fmaxf(t0, 0.f);
      tss[p * 20 + cr0 + 1] = fmaxf(t1, 0.f);
    }
  }
  __syncthreads();

  // ---- Phase C: span. wave w_ owns uniform pairs (g*49+k) = w_ + 8j.
  {
    float tv[16];
#pragma unroll
    for (int i = 0; i < 4; i++) {
      float4 t4 = *(const float4*)&tss[p * 20 + 4 * i];
      tv[4 * i] = t4.x; tv[4 * i + 1] = t4.y;
      tv[4 * i + 2] = t4.z; tv[4 * i + 3] = t4.w;
    }
    __syncthreads();                   // tss reads done; tail may be overwritten
#pragma unroll
    for (int j = 0; j < 24; j++) {
      int pair = w_ + 8 * j;           // wave-uniform
      int gc = (pair * 669) >> 15;     // pair/49
      const float* wk = wspan + pair * 16;   // uniform -> s_load_dwordx16
      float a = bsp_l[pair];
#pragma unroll
      for (int i = 0; i < 16; i++) a = fmaf(tv[i], wk[i], a);
      if (ln < 32) wvs[pair * 32 + gc * 8 + pcol * 4 + prow] = a;
    }
    if (w_ < 4) {                      // tail: pair = 192..195 (gc = 3)
      int pair = w_ + 192;
      const float* wk = wspan + pair * 16;
      float a = bsp_l[pair];
#pragma unroll
      for (int i = 0; i < 16; i++) a = fmaf(tv[i], wk[i], a);
      if (ln < 32) wvs[pair * 32 + 24 + pcol * 4 + prow] = a;
    }
  }
  __syncthreads();

  // ---- Phase D: einsum. wave = output column w_, lane = channel.
  float acc0 = 0.f, acc1 = 0.f, acc2 = 0.f, acc3 = 0.f;
  {
    int c = ln;
    int gb = (ln >> 4) * 1576;         // g*(49*32+8): skewed base, distinct quads
    const float* xc = &xs[c * 141];    // lanes stride 141 (odd): conflict-free
    float xw[4][7];
#pragma unroll
    for (int r = 0; r < 4; r++)
#pragma unroll
      for (int kx = 0; kx < 7; kx++)
        xw[r][kx] = xc[r * 14 + w_ + kx];
#pragma unroll
    for (int ky = 0; ky < 7; ky++) {
      if (ky > 0) {
#pragma unroll
        for (int r = 0; r < 3; r++)
#pragma unroll
          for (int kx = 0; kx < 7; kx++) xw[r][kx] = xw[r + 1][kx];
#pragma unroll
        for (int kx = 0; kx < 7; kx++)
          xw[3][kx] = xc[(ky + 3) * 14 + w_ + kx];
      }
#pragma unroll
      for (int kx = 0; kx < 7; kx++) {
        int k = ky * 7 + kx;
        float4 w4 = *(const float4*)&wvs[gb + k * 32 + w_ * 4];
        acc0 = fmaf(w4.x, xw[0][kx], acc0);
        acc1 = fmaf(w4.y, xw[1][kx], acc1);
        acc2 = fmaf(w4.z, xw[2][kx], acc2);
        acc3 = fmaf(w4.w, xw[3][kx], acc3);
      }
    }
  }
  __syncthreads();                     // xs reads done; safe to alias with ob

  // ---- Phase E: transpose via LDS, coalesced store (+outer ReLU)
  {
    int c = ln;
    ob[c * 33 + 0 * 8 + w_] = fmaxf(acc0, 0.f);
    ob[c * 33 + 1 * 8 + w_] = fmaxf(acc1, 0.f);
    ob[c * 33 + 2 * 8 + w_] = fmaxf(acc2, 0.f);
    ob[c * 33 + 3 * 8 + w_] = fmaxf(acc3, 0.f);
  }
  __syncthreads();
  for (int j = tid; j < 2048; j += 512) {
    int c2 = j >> 5, pp = j & 31;
    int pr = pp >> 3, pc2 = pp & 7;
    int gy = oy0 + pr, gx = ox0 + pc2;
    if (gy < IH && gx < IW)
      y[c2 * HW + gy * IW + gx] = ob[c2 * 33 + pp];
  }
}

// ---------------------------------------------------------------- conv_out prep
// w (128,64,3,3) -> wt2[oc>>1][ky][ci][kx][oc&1]
__global__ __launch_bounds__(256) void transpose_w_kernel(
    const float* __restrict__ w, float* __restrict__ wt2)
{
  int i = blockIdx.x * 256 + threadIdx.x;
  if (i >= 128 * 64 * 9) return;
  int oc = i / 576;
  int rem = i - oc * 576;
  int ci = rem / 9;
  int k = rem - ci * 9;
  int ky = k / 3, kx = k - ky * 3;
  wt2[(oc >> 1) * 1152 + ky * 384 + ci * 6 + kx * 2 + (oc & 1)] = w[i];
}

// ---------------------------------------------------------------- conv_out v6
// LDS for x (v4 lesson: no-LDS thrashes L1) + weight reuse (v2/v3 lesson:
// 1 FMA/weight-dword starves scalar path). Thread = 4 horiz px x 2 oc:
// each weight dword -> 4 FMA, each LDS x-read -> 8 FMA. Wave = 16x16 px tile,
// wave-uniform oc-pair -> s_load weights. x staged in 8-ch double-buffered
// chunks [ch][row*20+col] (pitch 20: b128 reads land 8 lanes/bank-quad = floor).
// Grid (64 tiles, 16 oc-groups) x 256 thr: 4 blocks/CU, 23 KB LDS.
__global__ __launch_bounds__(256, 4) void conv_out_kernel(
    const float* __restrict__ x, const float* __restrict__ wt2,
    const float* __restrict__ b, float* __restrict__ y)
{
  __shared__ __align__(16) float xls[2][8][360];   // 23,040 B (18 rows, pitch 20)
  int tid = threadIdx.x;
  int wv_ = __builtin_amdgcn_readfirstlane(tid >> 6);   // wave 0..3
  int ln = tid & 63;
  int tx = blockIdx.x & 7, ty = blockIdx.x >> 3;
  int rowb = ty * 16, colb = tx * 16;
  int oc0 = blockIdx.y * 8 + wv_ * 2;                   // wave-uniform

  int r_o = ln >> 2;            // 0..15 output row in tile
  int c4  = (ln & 3) * 4;       // 0,4,8,12 col-group base

  const float* wbp = wt2 + (oc0 >> 1) * 1152;
  float acc0[4], acc1[4];
  float bb0 = b[oc0], bb1 = b[oc0 + 1];
#pragma unroll
  for (int i = 0; i < 4; i++) { acc0[i] = bb0; acc1[i] = bb1; }

  // ---- stage chunk 0 (8 channels x 18x18, pitch 20)
  float st[11];
#pragma unroll
  for (int i = 0; i < 11; i++) {
    int idx = tid + i * 256;
    float v = 0.f;
    if (idx < 2592) {
      int ch = idx / 324;
      int rem = idx - ch * 324;
      int r = rem / 18, cc = rem - r * 18;
      int gr = rowb + r, gc = colb + cc;
      if (gr < IH && gc < IW) v = x[ch * HW + gr * IW + gc];
    }
    st[i] = v;
  }
#pragma unroll
  for (int i = 0; i < 11; i++) {
    int idx = tid + i * 256;
    if (idx < 2592) {
      int ch = idx / 324;
      int rem = idx - ch * 324;
      int r = rem / 18, cc = rem - r * 18;
      xls[0][ch][r * 20 + cc] = st[i];
    }
  }
  __syncthreads();

  for (int cq = 0; cq < 8; cq++) {
    int buf = cq & 1;
    // prefetch next chunk's globals into regs (latency overlaps compute)
    float nx[11];
    if (cq < 7) {
#pragma unroll
      for (int i = 0; i < 11; i++) {
        int idx = tid + i * 256;
        float v = 0.f;
        if (idx < 2592) {
          int ch = idx / 324;
          int rem = idx - ch * 324;
          int r = rem / 18, cc = rem - r * 18;
          int gr = rowb + r, gc = colb + cc;
          if (gr < IH && gc < IW) v = x[((cq + 1) * 8 + ch) * HW + gr * IW + gc];
        }
        nx[i] = v;
      }
    }
    // ---- compute this chunk
#pragma unroll
    for (int ky = 0; ky < 3; ky++) {
      const float* wk = wbp + ky * 384 + cq * 48;   // + ci*6 below (uniform)
#pragma unroll
      for (int ci = 0; ci < 8; ci++) {
        const float* xr = &xls[buf][ci][(r_o + ky) * 20 + c4];
        float4 x4 = *(const float4*)xr;
        float2 x2 = *(const float2*)(xr + 4);
        float xv[6] = {x4.x, x4.y, x4.z, x4.w, x2.x, x2.y};
        const float* wc = wk + ci * 6;
        float w00 = wc[0], w01 = wc[1];
        float w10 = wc[2], w11 = wc[3];
        float w20 = wc[4], w21 = wc[5];
#pragma unroll
        for (int px = 0; px < 4; px++) {
          float xa = xv[px], xb2 = xv[px + 1], xc2 = xv[px + 2];
          acc0[px] = fmaf(xa, w00, acc0[px]);
          acc1[px] = fmaf(xa, w01, acc1[px]);
          acc0[px] = fmaf(xb2, w10, acc0[px]);
          acc1[px] = fmaf(xb2, w11, acc1[px]);
          acc0[px] = fmaf(xc2, w20, acc0[px]);
          acc1[px] = fmaf(xc2, w21, acc1[px]);
        }
      }
    }
    if (cq < 7) {
#pragma unroll
      for (int i = 0; i < 11; i++) {
        int idx = tid + i * 256;
        if (idx < 2592) {
          int ch = idx / 324;
          int rem = idx - ch * 324;
          int r = rem / 18, cc = rem - r * 18;
          xls[buf ^ 1][ch][r * 20 + cc] = nx[i];
        }
      }
    }
    __syncthreads();
  }

  int orow = rowb + r_o, ocol = colb + c4;
  if (orow < OH && ocol < OW) {      // OW%4==0: float4 never straddles edge
    *(float4*)&y[oc0 * OHW + orow * OW + ocol] =
        make_float4(acc0[0], acc0[1], acc0[2], acc0[3]);
    *(float4*)&y[(oc0 + 1) * OHW + orow * OW + ocol] =
        make_float4(acc1[0], acc1[1], acc1[2], acc1[3]);
  }
}

// ---------------------------------------------------------------- launch
extern "C" void kernel_launch(void* const* d_in, const int* in_sizes, int n_in,
                              void* d_out, int out_size, void* d_ws, size_t ws_size,
                              hipStream_t stream)
{
  const float* input = (const float*)d_in[0];
  const float* ciw   = (const float*)d_in[1];
  const float* cib   = (const float*)d_in[2];
  const float* wred  = (const float*)d_in[3];
  const float* bred  = (const float*)d_in[4];
  const float* gam   = (const float*)d_in[5];
  const float* bet   = (const float*)d_in[6];
  const float* mu    = (const float*)d_in[7];
  const float* var   = (const float*)d_in[8];
  const float* wspan = (const float*)d_in[9];
  const float* bspan = (const float*)d_in[10];
  const float* cow   = (const float*)d_in[11];
  const float* cob   = (const float*)d_in[12];
  float* out = (float*)d_out;

  float* bufA = (float*)d_ws;                 // 64*126*126 = 1,016,064 floats
  float* bufB = bufA + (1 << 20);             // @ 4 MiB
  float* wt   = bufA + (1 << 21);             // @ 8 MiB, 73,728 floats

  transpose_w_kernel<<<288, 256, 0, stream>>>(cow, wt);
  conv_in_kernel<<<dim3(63, 64), 256, 0, stream>>>(input, ciw, cib, bufA);

  float* cur = bufA; float* nxt = bufB;
  for (int i = 0; i < 6; i++) {
    inv_kernel<<<512, 512, 0, stream>>>(cur, nxt,
        wred + i * 16 * 64, bred + i * 16, gam + i * 16, bet + i * 16,
        mu + i * 16, var + i * 16, wspan + i * 196 * 16, bspan + i * 196);
    float* t = cur; cur = nxt; nxt = t;
  }
  conv_out_kernel<<<dim3(64, 16), 256, 0, stream>>>(cur, wt, cob, out);
}

// Round 6
// 334.422 us; speedup vs baseline: 1.8605x; 1.8605x over previous
//
#include <hip/hip_runtime.h>

#define IH 126
#define IW 126
#define HW 15876      // 126*126
#define OH 124
#define OW 124
#define OHW 15376     // 124*124

// ---------------------------------------------------------------- conv_in
__global__ __launch_bounds__(256) void conv_in_kernel(
    const float* __restrict__ x, const float* __restrict__ w,
    const float* __restrict__ b, float* __restrict__ y)
{
  int pix = blockIdx.x * 256 + threadIdx.x;
  if (pix >= HW) return;
  int oc = blockIdx.y;                 // wave-uniform -> weights become s_loads
  int h  = pix / IW;
  int wc = pix - h * IW;
  const float* wp = w + oc * 27;
  float acc = b[oc];
#pragma unroll
  for (int ci = 0; ci < 3; ci++)
#pragma unroll
    for (int ky = 0; ky < 3; ky++)
#pragma unroll
      for (int kx = 0; kx < 3; kx++)
        acc = fmaf(x[ci * 128 * 128 + (h + ky) * 128 + (wc + kx)],
                   wp[ci * 9 + ky * 3 + kx], acc);
  y[oc * HW + pix] = acc;
}

// ---------------------------------------------------------------- involution v5
// (unchanged from round 5 — passed; ~31 µs/layer by subtraction)
__global__ __launch_bounds__(512, 4) void inv_kernel(
    const float* __restrict__ x, float* __restrict__ y,
    const float* __restrict__ wr, const float* __restrict__ br,
    const float* __restrict__ gam, const float* __restrict__ bet,
    const float* __restrict__ mu, const float* __restrict__ var,
    const float* __restrict__ wspan, const float* __restrict__ bspan)
{
  __shared__ __align__(16) float xs[64 * 141];   // 36,096 B  [c][pos 14x10+pad]
  __shared__ __align__(16) float wvs[6296];      // 25,184 B  skewed pair*32+g*8
  __shared__ float bsp_l[196];                   //    784 B
  float* tss = &wvs[5656];                       // [32][20] overlap tail
  float* ob  = &xs[0];                           // [64][33] alias in phase E

  int tid = threadIdx.x;
  int bx = blockIdx.x & 15, by = blockIdx.x >> 4;
  int ox0 = bx * 8, oy0 = by * 4;
  int xh0 = ox0 - 3, yh0 = oy0 - 3;

  // ---- Phase A: stage x halo (14 cols x 10 rows x 64 ch) + bspan
  if (tid < 196) bsp_l[tid] = bspan[tid];
  for (int idx = tid; idx < 140 * 64; idx += 512) {
    int c = idx / 140;
    int pos = idx - c * 140;
    int row = pos / 14;
    int col = pos - row * 14;
    int gy = yh0 + row, gx = xh0 + col;
    float v = 0.f;
    if (gy >= 0 && gy < IH && gx >= 0 && gx < IW)
      v = x[c * HW + gy * IW + gx];
    xs[c * 141 + pos] = v;             // lanes consecutive pos: stride-1, free
  }
  __syncthreads();

  int w_ = __builtin_amdgcn_readfirstlane(tid >> 6);  // wave 0..7
  int ln = tid & 63;
  int p  = ln & 31;                   // pixel 0..31 (upper 32 lanes duplicate)
  int prow = p >> 3, pcol = p & 7;
  int pc = (prow + 3) * 14 + (pcol + 3);

  // ---- Phase B: t = ReLU(BN(Wr.x)); wave w_ does cr = 2w_, 2w_+1 (uniform)
  {
    int cr0 = 2 * w_;
    const float* wa = wr + cr0 * 64;  // uniform -> s_load
    const float* wb = wa + 64;
    float a0 = 0.f, a1 = 0.f;
#pragma unroll
    for (int ci = 0; ci < 64; ci++) {
      float xv = xs[ci * 141 + pc];   // lanes: 32 distinct pc, 2-way dup: free
      a0 = fmaf(xv, wa[ci], a0);
      a1 = fmaf(xv, wb[ci], a1);
    }
    float s0 = gam[cr0]     * rsqrtf(var[cr0]     + 1e-5f);
    float s1 = gam[cr0 + 1] * rsqrtf(var[cr0 + 1] + 1e-5f);
    float t0 = (a0 + br[cr0]     - mu[cr0])     * s0 + bet[cr0];
    float t1 = (a1 + br[cr0 + 1] - mu[cr0 + 1]) * s1 + bet[cr0 + 1];
    if (ln < 32) {
      tss[p * 20 + cr0]     = fmaxf(t0, 0.f);
      tss[p * 20 + cr0 + 1] = fmaxf(t1, 0.f);
    }
  }
  __syncthreads();

  // ---- Phase C: span. wave w_ owns uniform pairs (g*49+k) = w_ + 8j.
  {
    float tv[16];
#pragma unroll
    for (int i = 0; i < 4; i++) {
      float4 t4 = *(const float4*)&tss[p * 20 + 4 * i];
      tv[4 * i] = t4.x; tv[4 * i + 1] = t4.y;
      tv[4 * i + 2] = t4.z; tv[4 * i + 3] = t4.w;
    }
    __syncthreads();                   // tss reads done; tail may be overwritten
#pragma unroll
    for (int j = 0; j < 24; j++) {
      int pair = w_ + 8 * j;           // wave-uniform
      int gc = (pair * 669) >> 15;     // pair/49
      const float* wk = wspan + pair * 16;   // uniform -> s_load_dwordx16
      float a = bsp_l[pair];
#pragma unroll
      for (int i = 0; i < 16; i++) a = fmaf(tv[i], wk[i], a);
      if (ln < 32) wvs[pair * 32 + gc * 8 + pcol * 4 + prow] = a;
    }
    if (w_ < 4) {                      // tail: pair = 192..195 (gc = 3)
      int pair = w_ + 192;
      const float* wk = wspan + pair * 16;
      float a = bsp_l[pair];
#pragma unroll
      for (int i = 0; i < 16; i++) a = fmaf(tv[i], wk[i], a);
      if (ln < 32) wvs[pair * 32 + 24 + pcol * 4 + prow] = a;
    }
  }
  __syncthreads();

  // ---- Phase D: einsum. wave = output column w_, lane = channel.
  float acc0 = 0.f, acc1 = 0.f, acc2 = 0.f, acc3 = 0.f;
  {
    int gb = (ln >> 4) * 1576;         // g*(49*32+8): skewed base, distinct quads
    const float* xc = &xs[ln * 141];   // lanes stride 141 (odd): conflict-free
    float xw[4][7];
#pragma unroll
    for (int r = 0; r < 4; r++)
#pragma unroll
      for (int kx = 0; kx < 7; kx++)
        xw[r][kx] = xc[r * 14 + w_ + kx];
#pragma unroll
    for (int ky = 0; ky < 7; ky++) {
      if (ky > 0) {
#pragma unroll
        for (int r = 0; r < 3; r++)
#pragma unroll
          for (int kx = 0; kx < 7; kx++) xw[r][kx] = xw[r + 1][kx];
#pragma unroll
        for (int kx = 0; kx < 7; kx++)
          xw[3][kx] = xc[(ky + 3) * 14 + w_ + kx];
      }
#pragma unroll
      for (int kx = 0; kx < 7; kx++) {
        int k = ky * 7 + kx;
        float4 w4 = *(const float4*)&wvs[gb + k * 32 + w_ * 4];
        acc0 = fmaf(w4.x, xw[0][kx], acc0);
        acc1 = fmaf(w4.y, xw[1][kx], acc1);
        acc2 = fmaf(w4.z, xw[2][kx], acc2);
        acc3 = fmaf(w4.w, xw[3][kx], acc3);
      }
    }
  }
  __syncthreads();                     // xs reads done; safe to alias with ob

  // ---- Phase E: transpose via LDS, coalesced store (+outer ReLU)
  {
    int c = ln;
    ob[c * 33 + 0 * 8 + w_] = fmaxf(acc0, 0.f);
    ob[c * 33 + 1 * 8 + w_] = fmaxf(acc1, 0.f);
    ob[c * 33 + 2 * 8 + w_] = fmaxf(acc2, 0.f);
    ob[c * 33 + 3 * 8 + w_] = fmaxf(acc3, 0.f);
  }
  __syncthreads();
  for (int j = tid; j < 2048; j += 512) {
    int c2 = j >> 5, pp = j & 31;
    int pr = pp >> 3, pc2 = pp & 7;
    int gy = oy0 + pr, gx = ox0 + pc2;
    if (gy < IH && gx < IW)
      y[c2 * HW + gy * IW + gx] = ob[c2 * 33 + pp];
  }
}

// ---------------------------------------------------------------- conv_out prep
// w (128,64,3,3) -> wt2[oc>>1][ky][ci][kx][oc&1]
__global__ __launch_bounds__(256) void transpose_w_kernel(
    const float* __restrict__ w, float* __restrict__ wt2)
{
  int i = blockIdx.x * 256 + threadIdx.x;
  if (i >= 128 * 64 * 9) return;
  int oc = i / 576;
  int rem = i - oc * 576;
  int ci = rem / 9;
  int k = rem - ci * 9;
  int ky = k / 3, kx = k - ky * 3;
  wt2[(oc >> 1) * 1152 + ky * 384 + ci * 6 + kx * 2 + (oc & 1)] = w[i];
}

// ---------------------------------------------------------------- conv_out v7
// v6's compute core (4 horiz px x 2 oc/thread: weight dword -> 4 FMA, x dword
// -> ~8 FMA, wave-uniform oc-pair -> s_load weights) with SPILL-PROOF staging:
// single-buffered 16-channel LDS chunks, direct global->LDS loop, no register
// arrays (v6's register double-buffer went to scratch: 1.5 GB HBM spill).
// Tile 16x16, grid (64 tiles, 16 oc-groups) x 256 thr, LDS 23 KB.
__global__ __launch_bounds__(256) void conv_out_kernel(
    const float* __restrict__ x, const float* __restrict__ wt2,
    const float* __restrict__ b, float* __restrict__ y)
{
  __shared__ __align__(16) float xls[16 * 360];   // 23,040 B (16 ch, 18 rows, pitch 20)
  int tid = threadIdx.x;
  int wv_ = __builtin_amdgcn_readfirstlane(tid >> 6);   // wave 0..3
  int ln = tid & 63;
  int tx = blockIdx.x & 7, ty = blockIdx.x >> 3;
  int rowb = ty * 16, colb = tx * 16;
  int oc0 = blockIdx.y * 8 + wv_ * 2;                   // wave-uniform

  int r_o = ln >> 2;            // 0..15 output row in tile
  int c4  = (ln & 3) * 4;       // 0,4,8,12 col-group base

  const float* wbp = wt2 + (oc0 >> 1) * 1152;
  float acc0[4], acc1[4];
  float bb0 = b[oc0], bb1 = b[oc0 + 1];
#pragma unroll
  for (int i = 0; i < 4; i++) { acc0[i] = bb0; acc1[i] = bb1; }

#pragma unroll 1
  for (int cq = 0; cq < 4; cq++) {
    __syncthreads();             // previous chunk's reads complete
    // ---- stage 16 channels x 18x18 (pitch 20), direct to LDS
    for (int idx = tid; idx < 5760; idx += 256) {
      int ch = idx / 360;
      int rem = idx - ch * 360;
      int r = rem / 20, ccol = rem - r * 20;
      int gr = rowb + r, gc = colb + ccol;
      float v = 0.f;
      if (ccol < 18 && gr < IH && gc < IW)
        v = x[(cq * 16 + ch) * HW + gr * IW + gc];
      xls[idx] = v;
    }
    __syncthreads();
    // ---- compute 16 channels
#pragma unroll
    for (int ky = 0; ky < 3; ky++) {
      const float* wk = wbp + ky * 384 + cq * 96;   // + ci*6 (uniform)
#pragma unroll
      for (int ci = 0; ci < 16; ci++) {
        const float* xr = &xls[ci * 360 + (r_o + ky) * 20 + c4];
        float4 x4 = *(const float4*)xr;
        float2 x2 = *(const float2*)(xr + 4);
        float xv0 = x4.x, xv1 = x4.y, xv2 = x4.z;
        float xv3 = x4.w, xv4 = x2.x, xv5 = x2.y;
        const float* wc = wk + ci * 6;
        float w00 = wc[0], w01 = wc[1];
        float w10 = wc[2], w11 = wc[3];
        float w20 = wc[4], w21 = wc[5];
        acc0[0] = fmaf(xv0, w00, acc0[0]); acc1[0] = fmaf(xv0, w01, acc1[0]);
        acc0[0] = fmaf(xv1, w10, acc0[0]); acc1[0] = fmaf(xv1, w11, acc1[0]);
        acc0[0] = fmaf(xv2, w20, acc0[0]); acc1[0] = fmaf(xv2, w21, acc1[0]);
        acc0[1] = fmaf(xv1, w00, acc0[1]); acc1[1] = fmaf(xv1, w01, acc1[1]);
        acc0[1] = fmaf(xv2, w10, acc0[1]); acc1[1] = fmaf(xv2, w11, acc1[1]);
        acc0[1] = fmaf(xv3, w20, acc0[1]); acc1[1] = fmaf(xv3, w21, acc1[1]);
        acc0[2] = fmaf(xv2, w00, acc0[2]); acc1[2] = fmaf(xv2, w01, acc1[2]);
        acc0[2] = fmaf(xv3, w10, acc0[2]); acc1[2] = fmaf(xv3, w11, acc1[2]);
        acc0[2] = fmaf(xv4, w20, acc0[2]); acc1[2] = fmaf(xv4, w21, acc1[2]);
        acc0[3] = fmaf(xv3, w00, acc0[3]); acc1[3] = fmaf(xv3, w01, acc1[3]);
        acc0[3] = fmaf(xv4, w10, acc0[3]); acc1[3] = fmaf(xv4, w11, acc1[3]);
        acc0[3] = fmaf(xv5, w20, acc0[3]); acc1[3] = fmaf(xv5, w21, acc1[3]);
      }
    }
  }

  int orow = rowb + r_o, ocol = colb + c4;
  if (orow < OH && ocol < OW) {      // OW%4==0: float4 never straddles edge
    *(float4*)&y[oc0 * OHW + orow * OW + ocol] =
        make_float4(acc0[0], acc0[1], acc0[2], acc0[3]);
    *(float4*)&y[(oc0 + 1) * OHW + orow * OW + ocol] =
        make_float4(acc1[0], acc1[1], acc1[2], acc1[3]);
  }
}

// ---------------------------------------------------------------- launch
extern "C" void kernel_launch(void* const* d_in, const int* in_sizes, int n_in,
                              void* d_out, int out_size, void* d_ws, size_t ws_size,
                              hipStream_t stream)
{
  const float* input = (const float*)d_in[0];
  const float* ciw   = (const float*)d_in[1];
  const float* cib   = (const float*)d_in[2];
  const float* wred  = (const float*)d_in[3];
  const float* bred  = (const float*)d_in[4];
  const float* gam   = (const float*)d_in[5];
  const float* bet   = (const float*)d_in[6];
  const float* mu    = (const float*)d_in[7];
  const float* var   = (const float*)d_in[8];
  const float* wspan = (const float*)d_in[9];
  const float* bspan = (const float*)d_in[10];
  const float* cow   = (const float*)d_in[11];
  const float* cob   = (const float*)d_in[12];
  float* out = (float*)d_out;

  float* bufA = (float*)d_ws;                 // 64*126*126 = 1,016,064 floats
  float* bufB = bufA + (1 << 20);             // @ 4 MiB
  float* wt   = bufA + (1 << 21);             // @ 8 MiB, 73,728 floats

  transpose_w_kernel<<<288, 256, 0, stream>>>(cow, wt);
  conv_in_kernel<<<dim3(63, 64), 256, 0, stream>>>(input, ciw, cib, bufA);

  float* cur = bufA; float* nxt = bufB;
  for (int i = 0; i < 6; i++) {
    inv_kernel<<<512, 512, 0, stream>>>(cur, nxt,
        wred + i * 16 * 64, bred + i * 16, gam + i * 16, bet + i * 16,
        mu + i * 16, var + i * 16, wspan + i * 196 * 16, bspan + i * 196);
    float* t = cur; cur = nxt; nxt = t;
  }
  conv_out_kernel<<<dim3(64, 16), 256, 0, stream>>>(cur, wt, cob, out);
}